// Round 18
// baseline (474.934 us; speedup 1.0000x reference)
//
#include <hip/hip_runtime.h>
#include <hip/hip_cooperative_groups.h>

namespace cg = cooperative_groups;

#define BB 32
#define CC 128
#define HH 128
#define WW 128
#define HWSZ (HH * WW)          // 16384
#define CHW (CC * HWSZ)         // 2097152
#define S4 (HWSZ / 4)           // 4096

typedef float vfloat4 __attribute__((ext_vector_type(4)));

__device__ __forceinline__ vfloat4 fmax4(vfloat4 a, vfloat4 b) {
    vfloat4 r;
    r.x = fmaxf(a.x, b.x);
    r.y = fmaxf(a.y, b.y);
    r.z = fmaxf(a.z, b.z);
    r.w = fmaxf(a.w, b.w);
    return r;
}

// ============ PLAN A: persistent cooperative kernel, x read ONCE ============
// 256 blocks x 512 threads, 1 block/CU. 4 generations x 8 batches.
// Block owns a 4-row band; x slab (4 rows x 128 ch) lives in REGISTERS
// (32 float4/thread) across reduce -> grid.sync -> conv -> multiply.
__global__ __launch_bounds__(512, 2) void sa_coop(
    const float* __restrict__ x, const float* __restrict__ cw,
    float* __restrict__ out, float* __restrict__ maps) {
    __shared__ float psum_s[4][4][WW];   // [cg][r][w]  8 KiB
    __shared__ float psum_m[4][4][WW];   // 8 KiB
    __shared__ float m_lds[2][10][WW];   // halo rows   10 KiB
    __shared__ float sig_lds[4][WW];     // 2 KiB
    __shared__ float wsh[2 * 49];

    const int tid = threadIdx.x;
    const int blk = blockIdx.x;          // 0..255
    // XCD-friendly: 4 contiguous bands of a batch per XCD.
    const int xcd = blk & 7;
    const int lin = blk >> 3;            // 0..31
    const int bq  = lin >> 2;            // batch-within-generation 0..7
    const int band = xcd * 4 + (lin & 3);// 0..31
    const int h0 = band * 4;

    // thread mapping (phases A and C): t = cg*128 + r*32 + w4
    const int cgp = tid >> 7;            // 0..3  channel group (32 ch each)
    const int rp  = (tid >> 5) & 3;      // 0..3  row in band
    const int w4p = tid & 31;            // float4 column

    if (tid < 98) wsh[tid] = cw[tid];

    cg::grid_group grid = cg::this_grid();

    vfloat4 v[32];                       // x slab: 32 channels of (row rp, col w4p)

    for (int g = 0; g < 4; ++g) {
        __syncthreads();                 // protect psum/m_lds/sig reuse across gens
        const int b = g * 8 + bq;
        const float* xb = x + (size_t)b * CHW;

        // ---------- Phase A: load x slab to regs + channel partial reduce ----
        {
            const float* base = xb + (size_t)(cgp * 32) * HWSZ + (h0 + rp) * WW;
            vfloat4 s, m;
            v[0] = *((const vfloat4*)base + w4p);
            s = v[0]; m = v[0];
            #pragma unroll
            for (int i = 1; i < 32; ++i) {
                v[i] = *((const vfloat4*)(base + (size_t)i * HWSZ) + w4p);
                s += v[i];
                m = fmax4(m, v[i]);
            }
            *(vfloat4*)&psum_s[cgp][rp][w4p * 4] = s;
            *(vfloat4*)&psum_m[cgp][rp][w4p * 4] = m;
        }
        __syncthreads();
        if (tid < 128) {                 // combine 4 cg partials; publish maps
            const int r = tid >> 5, w4 = tid & 31;
            vfloat4 s = *(vfloat4*)&psum_s[0][r][w4 * 4];
            vfloat4 m = *(vfloat4*)&psum_m[0][r][w4 * 4];
            #pragma unroll
            for (int c = 1; c < 4; ++c) {
                s += *(vfloat4*)&psum_s[c][r][w4 * 4];
                m = fmax4(m, *(vfloat4*)&psum_m[c][r][w4 * 4]);
            }
            vfloat4 avg = s * (1.0f / (float)CC);
            *(vfloat4*)&m_lds[0][3 + r][w4 * 4] = avg;   // stash own rows (halo idx 3..6)
            *(vfloat4*)&m_lds[1][3 + r][w4 * 4] = m;
            *((vfloat4*)(maps + ((size_t)b * 2 + 0) * HWSZ + (h0 + r) * WW) + w4) = avg;
            *((vfloat4*)(maps + ((size_t)b * 2 + 1) * HWSZ + (h0 + r) * WW) + w4) = m;
        }
        __threadfence();
        grid.sync();                     // all maps of this generation visible

        // ---------- Phase B: stage 6 neighbor halo rows + conv + sigmoid ----
        if (tid < 384) {                 // 2 ic x 6 rows x 32 w4
            const int ic = tid / 192;
            const int rem = tid - ic * 192;
            const int ridx = rem >> 5;   // 0..5
            const int w4 = rem & 31;
            const int rr = (ridx < 3) ? ridx : ridx + 4;     // halo row 0..2, 7..9
            const int gh = h0 - 3 + rr;
            vfloat4 val = {0.f, 0.f, 0.f, 0.f};
            if (gh >= 0 && gh < HH)
                val = *((const vfloat4*)(maps + ((size_t)b * 2 + ic) * HWSZ + gh * WW) + w4);
            *(vfloat4*)&m_lds[ic][rr][w4 * 4] = val;
        }
        __syncthreads();
        {
            const int r = tid >> 7;      // 0..3
            const int w = tid & 127;
            float attn = 0.f;
            #pragma unroll
            for (int ic = 0; ic < 2; ++ic) {
                #pragma unroll
                for (int kh = 0; kh < 7; ++kh) {
                    const float* row = &m_lds[ic][r + kh][0];
                    #pragma unroll
                    for (int kw = 0; kw < 7; ++kw) {
                        int wi = w - 3 + kw;
                        float vv = (wi >= 0 && wi < WW) ? row[wi] : 0.0f;
                        attn = fmaf(vv, wsh[ic * 49 + kh * 7 + kw], attn);
                    }
                }
            }
            sig_lds[r][w] = 1.0f / (1.0f + __expf(-attn));
        }
        __syncthreads();

        // ---------- Phase C: multiply reg-held x, nt-store ----
        {
            vfloat4 sg = *(const vfloat4*)&sig_lds[rp][w4p * 4];
            float* ob = out + (size_t)b * CHW + (size_t)(cgp * 32) * HWSZ + (h0 + rp) * WW;
            #pragma unroll
            for (int i = 0; i < 32; ++i)
                __builtin_nontemporal_store(v[i] * sg, (vfloat4*)(ob + (size_t)i * HWSZ) + w4p);
        }
    }
}

// =================== PLAN B: R12 champion (two kernels) ===================
#define RPB 8
#define HALO 14

__global__ __launch_bounds__(256) void k1_reduce(
    const float* __restrict__ x, float* __restrict__ maps) {
    const int tid = threadIdx.x;
    const int wg  = blockIdx.x;
    const int b   = wg >> 4;
    const int hb  = wg & 15;
    const int gh  = hb * RPB + (tid >> 5);
    const int w4  = tid & 31;

    const vfloat4* p = (const vfloat4*)(x + (size_t)b * CHW + gh * WW) + w4;
    vfloat4 v = p[0];
    vfloat4 sum = v, mx = v;
    #pragma unroll 8
    for (int c = 1; c < CC; ++c) {
        vfloat4 t = p[(size_t)c * S4];
        sum += t;
        mx = fmax4(mx, t);
    }
    vfloat4 avg = sum * (1.0f / (float)CC);
    *((vfloat4*)(maps + ((size_t)b * 2 + 0) * HWSZ + gh * WW) + w4) = avg;
    *((vfloat4*)(maps + ((size_t)b * 2 + 1) * HWSZ + gh * WW) + w4) = mx;
}

__global__ __launch_bounds__(256, 2) void k2_conv_mul(
    const float* __restrict__ x, const float* __restrict__ maps,
    const float* __restrict__ cw, float* __restrict__ out) {
    __shared__ float m_lds[2][HALO][WW];
    __shared__ float sig_lds[RPB][WW];
    __shared__ float wsh[2 * 49];

    const int tid = threadIdx.x;
    const int wg  = blockIdx.x;
    const int xcd = wg & 7;
    const int lin = wg >> 3;
    const int b   = xcd * 4 + (lin >> 4);
    const int hb  = lin & 15;
    const int h0  = hb * RPB;

    if (tid < 98) wsh[tid] = cw[tid];

    for (int i = tid; i < 2 * HALO * 32; i += 256) {
        const int ic = i / (HALO * 32);
        const int rem = i - ic * (HALO * 32);
        const int rr = rem >> 5;
        const int w4 = rem & 31;
        const int gh = h0 - 3 + rr;
        vfloat4 v = {0.f, 0.f, 0.f, 0.f};
        if (gh >= 0 && gh < HH)
            v = *((const vfloat4*)(maps + ((size_t)b * 2 + ic) * HWSZ + gh * WW) + w4);
        *(vfloat4*)&m_lds[ic][rr][w4 * 4] = v;
    }
    __syncthreads();

    {
        const int q = tid >> 7;
        const int w = tid & 127;
        float attn[4] = {0.f, 0.f, 0.f, 0.f};
        #pragma unroll
        for (int ic = 0; ic < 2; ++ic) {
            #pragma unroll
            for (int L = 0; L < 10; ++L) {
                const float* row = &m_lds[ic][q * 4 + L][0];
                #pragma unroll
                for (int kw = 0; kw < 7; ++kw) {
                    int wi = w - 3 + kw;
                    float v = (wi >= 0 && wi < WW) ? row[wi] : 0.0f;
                    #pragma unroll
                    for (int j = 0; j < 4; ++j) {
                        const int kh = L - j;
                        if (kh >= 0 && kh <= 6)
                            attn[j] = fmaf(v, wsh[ic * 49 + kh * 7 + kw], attn[j]);
                    }
                }
            }
        }
        #pragma unroll
        for (int j = 0; j < 4; ++j)
            sig_lds[q * 4 + j][w] = 1.0f / (1.0f + __expf(-attn[j]));
    }
    __syncthreads();

    {
        const float* xb = x + (size_t)b * CHW;
        const int wv = tid >> 6;
        const int ln = tid & 63;
        vfloat4 sgv[4];
        #pragma unroll
        for (int j = 0; j < 4; ++j) {
            int idx = ln + 64 * j;
            sgv[j] = *(const vfloat4*)&sig_lds[idx >> 5][(idx & 31) * 4];
        }
        const size_t slab_off = (size_t)h0 * WW;
        #pragma unroll 2
        for (int k = 31; k >= 0; --k) {
            const int c = wv + 4 * k;
            const vfloat4* ps = (const vfloat4*)(xb + (size_t)c * HWSZ + slab_off);
            vfloat4* po = (vfloat4*)(out + (size_t)b * CHW + (size_t)c * HWSZ + slab_off);
            vfloat4 v0 = ps[ln];
            vfloat4 v1 = ps[ln + 64];
            vfloat4 v2 = ps[ln + 128];
            vfloat4 v3 = ps[ln + 192];
            __builtin_nontemporal_store(v0 * sgv[0], po + ln);
            __builtin_nontemporal_store(v1 * sgv[1], po + ln + 64);
            __builtin_nontemporal_store(v2 * sgv[2], po + ln + 128);
            __builtin_nontemporal_store(v3 * sgv[3], po + ln + 192);
        }
    }
}

// =================== FALLBACK (ws < 4 MiB): fused champion ===================
__global__ __launch_bounds__(256, 2) void sa_onepass(
    const float* __restrict__ x, const float* __restrict__ cw,
    float* __restrict__ out) {
    __shared__ float m_lds[2][HALO][WW];
    __shared__ float sig_lds[RPB][WW];
    __shared__ float wsh[2 * 49];

    const int tid = threadIdx.x;
    const int wg  = blockIdx.x;
    const int xcd = wg & 7;
    const int lin = wg >> 3;
    const int b   = xcd * 4 + (lin >> 4);
    const int hb  = lin & 15;
    const int h0  = hb * RPB;

    if (tid < 98) wsh[tid] = cw[tid];

    const int r0 = tid >> 5;
    const int w4 = tid & 31;
    const float* xb = x + (size_t)b * CHW;

    const bool actB = (r0 < HALO - 8);
    const int gh_a = h0 - 3 + r0;
    const int gh_b = h0 - 3 + r0 + 8;
    const bool okA = (gh_a >= 0) && (gh_a < HH);
    const bool okB = actB && (gh_b < HH);
    const int cha = gh_a < 0 ? 0 : (gh_a > HH - 1 ? HH - 1 : gh_a);
    const int chb = gh_b > HH - 1 ? HH - 1 : gh_b;

    const vfloat4* pA = (const vfloat4*)(xb + cha * WW) + w4;
    const vfloat4* pB = (const vfloat4*)(xb + chb * WW) + w4;

    vfloat4 sumA, mxA;
    {
        vfloat4 v = pA[0];
        sumA = v; mxA = v;
    }
    #pragma unroll 8
    for (int c = 1; c < CC; ++c) {
        vfloat4 v = pA[(size_t)c * S4];
        sumA += v;
        mxA = fmax4(mxA, v);
    }
    vfloat4 sumB = {0.f, 0.f, 0.f, 0.f}, mxB = sumB;
    if (actB) {
        vfloat4 v = pB[0];
        sumB = v; mxB = v;
        #pragma unroll 8
        for (int c = 1; c < CC; ++c) {
            vfloat4 t = pB[(size_t)c * S4];
            sumB += t;
            mxB = fmax4(mxB, t);
        }
    }

    const float invC = 1.0f / (float)CC;
    {
        vfloat4 avgA = sumA * invC;
        if (!okA) { avgA = (vfloat4){0,0,0,0}; mxA = (vfloat4){0,0,0,0}; }
        *(vfloat4*)&m_lds[0][r0][w4 * 4] = avgA;
        *(vfloat4*)&m_lds[1][r0][w4 * 4] = mxA;
        if (actB) {
            vfloat4 avgB = sumB * invC;
            if (!okB) { avgB = (vfloat4){0,0,0,0}; mxB = (vfloat4){0,0,0,0}; }
            *(vfloat4*)&m_lds[0][r0 + 8][w4 * 4] = avgB;
            *(vfloat4*)&m_lds[1][r0 + 8][w4 * 4] = mxB;
        }
    }
    __syncthreads();

    {
        const int q = tid >> 7;
        const int w = tid & 127;
        float attn[4] = {0.f, 0.f, 0.f, 0.f};
        #pragma unroll
        for (int ic = 0; ic < 2; ++ic) {
            #pragma unroll
            for (int L = 0; L < 10; ++L) {
                const float* row = &m_lds[ic][q * 4 + L][0];
                #pragma unroll
                for (int kw = 0; kw < 7; ++kw) {
                    int wi = w - 3 + kw;
                    float v = (wi >= 0 && wi < WW) ? row[wi] : 0.0f;
                    #pragma unroll
                    for (int j = 0; j < 4; ++j) {
                        const int kh = L - j;
                        if (kh >= 0 && kh <= 6)
                            attn[j] = fmaf(v, wsh[ic * 49 + kh * 7 + kw], attn[j]);
                    }
                }
            }
        }
        #pragma unroll
        for (int j = 0; j < 4; ++j)
            sig_lds[q * 4 + j][w] = 1.0f / (1.0f + __expf(-attn[j]));
    }
    __syncthreads();

    {
        const int wv = tid >> 6;
        const int ln = tid & 63;
        vfloat4 sgv[4];
        #pragma unroll
        for (int j = 0; j < 4; ++j) {
            int idx = ln + 64 * j;
            sgv[j] = *(const vfloat4*)&sig_lds[idx >> 5][(idx & 31) * 4];
        }
        const size_t slab_off = (size_t)h0 * WW;
        #pragma unroll 2
        for (int k = 31; k >= 0; --k) {
            const int c = wv + 4 * k;
            const vfloat4* ps = (const vfloat4*)(xb + (size_t)c * HWSZ + slab_off);
            vfloat4* po = (vfloat4*)(out + (size_t)b * CHW + (size_t)c * HWSZ + slab_off);
            vfloat4 v0 = ps[ln];
            vfloat4 v1 = ps[ln + 64];
            vfloat4 v2 = ps[ln + 128];
            vfloat4 v3 = ps[ln + 192];
            __builtin_nontemporal_store(v0 * sgv[0], po + ln);
            __builtin_nontemporal_store(v1 * sgv[1], po + ln + 64);
            __builtin_nontemporal_store(v2 * sgv[2], po + ln + 128);
            __builtin_nontemporal_store(v3 * sgv[3], po + ln + 192);
        }
    }
}

extern "C" void kernel_launch(void* const* d_in, const int* in_sizes, int n_in,
                              void* d_out, int out_size, void* d_ws, size_t ws_size,
                              hipStream_t stream) {
    const float* x  = (const float*)d_in[0];
    const float* cw = (const float*)d_in[1];
    float* out = (float*)d_out;

    const size_t maps_bytes = (size_t)BB * 2 * HWSZ * sizeof(float);  // 4 MiB
    if (ws_size >= maps_bytes) {
        float* maps = (float*)d_ws;
        void* args[] = {(void*)&x, (void*)&cw, (void*)&out, (void*)&maps};
        hipError_t e = hipLaunchCooperativeKernel((void*)sa_coop, dim3(256), dim3(512),
                                                  args, 0, stream);
        if (e != hipSuccess) {
            // deterministic fallback: R12 champion path
            k1_reduce<<<BB * (HH / RPB), 256, 0, stream>>>(x, maps);
            k2_conv_mul<<<BB * (HH / RPB), 256, 0, stream>>>(x, maps, cw, out);
        }
    } else {
        sa_onepass<<<BB * (HH / RPB), 256, 0, stream>>>(x, cw, out);
    }
}